// Round 8
// baseline (216.521 us; speedup 1.0000x reference)
//
#include <hip/hip_runtime.h>
#include <hip/hip_bf16.h>

// CombinedModel R14: R13 structure + fp16 emb table (regime-correct retry of R8).
//   R13 post-mortem: occupancy 36->42.6% with BW flat at 2.6 TB/s => random-miss
//   stream is SERVICE-RATE saturated; more waves no longer help. In this regime
//   byte-cutting pays (it was null at 26% occ in R8 because latency, not BW,
//   bound). R8 proved the mechanism: FETCH 277->229MB, absmax bit-identical.
//   Changes vs R13 (single variable):
//     - prep kernel casts emb fp32 -> fp16 into d_ws (6.4MB, 64B rows)
//     - gather loads f16x4 (8B/lane, 8 lanes = full row) + 4 cvt per neighbor
//   Kept from R13: __launch_bounds__(256,5) (48-VGPR budget, spill-free),
//   W1+W2 frags in block-shared LDS (30KB/block, 5 blocks/CU), grid 1280,
//   fp32 gather fallback if ws too small, LDS-staged lat, split-bf16 MLP,
//   cross-chunk x/nbmap pipeline, wave-private slabs, single startup barrier.

typedef __attribute__((ext_vector_type(2))) float f32x2;
typedef __attribute__((ext_vector_type(4))) float f32x4;
typedef __attribute__((ext_vector_type(4))) int   i32x4;
typedef __attribute__((ext_vector_type(8))) short s16x8;
typedef __attribute__((ext_vector_type(4))) _Float16 f16x4;

#define GRID_W  2048
#define LSTR    36   // lat row stride (dwords): 144 B rows, 16B-aligned
#define PSTR    68   // h row stride (dwords): 272 B rows, 16B-aligned
#define W2OFF   (4 * 32 * LSTR)     // dword offset of W2 frag table (2048 dw)
#define W1OFF   (W2OFF + 2048)      // dword offset of W1 frag table (1024 dw)
#define SEL_HI  0x05040100u
#define SEL_LO  0x07060302u
#define LGKM0   0xC07F   // s_waitcnt vmcnt(63) expcnt(7) lgkmcnt(0): DS-only drain

static __device__ __forceinline__ unsigned bits_bf2(__hip_bfloat162 h) {
    union { __hip_bfloat162 b; unsigned u; } cv; cv.b = h; return cv.u;
}
// split (v0,v1) into bf16 hi + bf16 lo residual; packed dword_i = hi_i | lo_i<<16
static __device__ __forceinline__ void split2_packed(float v0, float v1, unsigned &p0, unsigned &p1) {
    float2 f; f.x = v0; f.y = v1;
    unsigned hu = bits_bf2(__float22bfloat162_rn(f));
    float2 d;
    d.x = v0 - __uint_as_float(hu << 16);
    d.y = v1 - __uint_as_float(hu & 0xffff0000u);
    unsigned lu = bits_bf2(__float22bfloat162_rn(d));
    p0 = (hu & 0xffffu) | (lu << 16);
    p1 = (hu >> 16) | (lu & 0xffff0000u);
}
static __device__ __forceinline__ s16x8 unpack8(uint4 q0, uint4 q1, unsigned sel) {
    union { unsigned u[4]; s16x8 v; } r;
    r.u[0] = __builtin_amdgcn_perm(q0.y, q0.x, sel);
    r.u[1] = __builtin_amdgcn_perm(q0.w, q0.z, sel);
    r.u[2] = __builtin_amdgcn_perm(q1.y, q1.x, sel);
    r.u[3] = __builtin_amdgcn_perm(q1.w, q1.z, sel);
    return r.v;
}
// single-bf16 weight fragment: 8 consecutive fp32 -> 8 bf16 (rtn)
static __device__ __forceinline__ s16x8 load_wbf(const float* p) {
    f32x4 a = ((const f32x4*)p)[0];
    f32x4 b = ((const f32x4*)p)[1];
    union { unsigned u[4]; s16x8 v; } r;
    float2 f;
    f.x = a.x; f.y = a.y; r.u[0] = bits_bf2(__float22bfloat162_rn(f));
    f.x = a.z; f.y = a.w; r.u[1] = bits_bf2(__float22bfloat162_rn(f));
    f.x = b.x; f.y = b.y; r.u[2] = bits_bf2(__float22bfloat162_rn(f));
    f.x = b.z; f.y = b.w; r.u[3] = bits_bf2(__float22bfloat162_rn(f));
    return r.v;
}
static __device__ __forceinline__ void lds_fence() {
    __builtin_amdgcn_wave_barrier();
    __builtin_amdgcn_s_waitcnt(LGKM0);
    __builtin_amdgcn_wave_barrier();
}

// ---- prep: emb fp32 -> fp16 (RTN), vectorized x4 ----
__global__ __launch_bounds__(256) void emb_cast_f16(
    const float* __restrict__ in, _Float16* __restrict__ out, int n4)
{
    int i = blockIdx.x * blockDim.x + threadIdx.x;
    int stride = gridDim.x * blockDim.x;
    for (; i < n4; i += stride) {
        f32x4 v = ((const f32x4*)in)[i];
        f16x4 o;
        o.x = (_Float16)v.x; o.y = (_Float16)v.y;
        o.z = (_Float16)v.z; o.w = (_Float16)v.w;
        ((f16x4*)out)[i] = o;
    }
}

template <bool F16>
__global__ __launch_bounds__(256, 5) void fused_persistent(
    const float* __restrict__ x,          // [N,2]
    const float* __restrict__ positions,  // [N_POS,2]
    const int*   __restrict__ nbmap,      // [H,W,4]
    const void*  __restrict__ embp,       // [N_POS,32] fp16 (ws) or fp32
    const float* __restrict__ W1,         // [64,32]
    const float* __restrict__ b1,         // [64]
    const float* __restrict__ W2,         // [64,64]
    const float* __restrict__ b2,         // [64]
    const float* __restrict__ W3,         // [3,64]
    const float* __restrict__ b3,         // [3]
    const float* __restrict__ mu,         // [3]
    const float* __restrict__ sd,         // [3]
    float* __restrict__ out,              // [N,3]
    int npts)
{
    const int tid  = threadIdx.x;
    const int w    = tid >> 6;
    const int lid  = tid & 63;
    const int quad = lid >> 4;
    const int m16  = lid & 15;
    const int c8   = lid & 7;    // gather: channel group (channels 4*c8 .. 4*c8+3)
    const int pr   = lid >> 3;   // gather: point row within pass (0..7)

    const int nwav = gridDim.x * 4;
    const int wgid = blockIdx.x * 4 + w;
    const int NCH  = (npts + 31) >> 5;

    // LDS: [0,W2OFF) 4 wave-private lat/h slabs; [W2OFF,+2048) W2; [W1OFF,+1024) W1
    __shared__ __align__(16) unsigned lat_lds[W1OFF + 1024];   // 30 KB total
    unsigned* latw = lat_lds + w * 32 * LSTR;   // wave-private 32-row slab
    unsigned* hb   = latw;                      // h-buffer overlays dead lat slab
    unsigned* w2b  = lat_lds + W2OFF;           // block-shared W2 frags
    unsigned* w1b  = lat_lds + W1OFF;           // block-shared W1 frags

    // ---- stage W2 + W1 frags into LDS (wave 0 only; frags depend only on lid) ----
    if (w == 0) {
#pragma unroll
        for (int s = 0; s < 2; ++s)
#pragma unroll
            for (int nt = 0; nt < 4; ++nt) {
                union { s16x8 v; uint4 q; } cv;
                cv.v = load_wbf(W2 + (nt * 16 + m16) * 64 + s * 32 + quad * 8);
                *(uint4*)(w2b + ((s * 4 + nt) * 64 + lid) * 4) = cv.q;
            }
#pragma unroll
        for (int nt = 0; nt < 4; ++nt) {
            union { s16x8 v; uint4 q; } cv;
            cv.v = load_wbf(W1 + (nt * 16 + m16) * 32 + quad * 8);
            *(uint4*)(w1b + (nt * 64 + lid) * 4) = cv.q;
        }
    }
    __syncthreads();             // ONLY block barrier (startup); all waves reach it
    if (wgid >= NCH) return;     // after barrier: safe

    const f32x2* Xv  = (const f32x2*)x;
    const f32x2* Pv  = (const f32x2*)positions;
    const i32x4* NBq = (const i32x4*)nbmap;

    // ---- per-wave weights kept in VGPR: W3 only (8 regs) ----
    s16x8 w3f[2];
#pragma unroll
    for (int s = 0; s < 2; ++s) {
        if (m16 < 3) {
            w3f[s] = load_wbf(W3 + m16 * 64 + s * 32 + quad * 8);
        } else {
            s16x8 z = {0, 0, 0, 0, 0, 0, 0, 0};
            w3f[s] = z;
        }
    }
    float b1v[4], b2v[4];
#pragma unroll
    for (int nt = 0; nt < 4; ++nt) { b1v[nt] = b1[nt * 16 + m16]; b2v[nt] = b2[nt * 16 + m16]; }
    const int mm = (m16 < 3) ? m16 : 0;
    const float b3m = b3[mm], sdm = sd[mm], mum = mu[mm];

    // ---- pipeline prologue: x + nbmap for first chunk ----
    f32x2 xv[4], xvn[4];
    i32x4 nb[4], nbn[4];
#pragma unroll
    for (int p = 0; p < 4; ++p) {
        int g = wgid * 32 + p * 8 + pr;
        g = (g < npts) ? g : (npts - 1);
        xv[p] = Xv[g];
    }
#pragma unroll
    for (int p = 0; p < 4; ++p) {
        int i0 = (int)xv[p].x, i1 = (int)xv[p].y;   // x >= 0: trunc == floor
        nb[p] = NBq[i0 * GRID_W + i1];
    }

    for (int c = wgid; c < NCH; c += nwav) {
        const int cn = c + nwav;
        const bool hn = (cn < NCH);

        // issue NEXT chunk's x loads now: ~1500 cyc before they're consumed
        if (hn) {
#pragma unroll
            for (int p = 0; p < 4; ++p) {
                int g = cn * 32 + p * 8 + pr;
                g = (g < npts) ? g : (npts - 1);
                xvn[p] = Xv[g];
            }
        }

        // ---- gather chunk c (nb[] already resident; pos/emb = 1 exposed RT) ----
#pragma unroll
        for (int p = 0; p < 4; ++p) {
            f32x2 xvp = xv[p];
            float f0 = (float)(int)xvp.x, f1 = (float)(int)xvp.y;
            i32x4 n4 = nb[p];
            int ids[4] = {n4.x, n4.y, n4.z, n4.w};
            float a0 = 0.f, a1 = 0.f, a2 = 0.f, a3 = 0.f;
#pragma unroll
            for (int k = 0; k < 4; ++k) {
                f32x2 pp = Pv[ids[k]];
                float dx = pp.x - f0, dy = pp.y - f1;
                float dist = sqrtf(dx * dx + dy * dy);
                float e0, e1, e2, e3;
                if constexpr (F16) {
                    const _Float16* E = (const _Float16*)embp;
                    f16x4 e = *(const f16x4*)(E + ids[k] * 32 + c8 * 4); // 8 lanes = 64B row
                    e0 = (float)e.x; e1 = (float)e.y; e2 = (float)e.z; e3 = (float)e.w;
                } else {
                    const float* E = (const float*)embp;
                    f32x4 e = *(const f32x4*)(E + ids[k] * 32 + c8 * 4); // 8 lanes = 128B row
                    e0 = e.x; e1 = e.y; e2 = e.z; e3 = e.w;
                }
                a0 = fmaf(dist, e0, a0); a1 = fmaf(dist, e1, a1);
                a2 = fmaf(dist, e2, a2); a3 = fmaf(dist, e3, a3);
            }
            unsigned p0, p1, p2, p3;
            split2_packed(a0, a1, p0, p1);
            split2_packed(a2, a3, p2, p3);
            uint4 pv; pv.x = p0; pv.y = p1; pv.z = p2; pv.w = p3;
            *(uint4*)(latw + (p * 8 + pr) * LSTR + c8 * 4) = pv;
        }
        lds_fence();

        // pre-read BOTH tiles' A-frags before hb overlay
        s16x8 AH[2], AL[2];
#pragma unroll
        for (int t = 0; t < 2; ++t) {
            const unsigned* ap = latw + (t * 16 + m16) * LSTR + quad * 8;
            uint4 q0 = *(const uint4*)ap;
            uint4 q1 = *(const uint4*)(ap + 4);
            AH[t] = unpack8(q0, q1, SEL_HI);
            AL[t] = unpack8(q0, q1, SEL_LO);
        }
        lds_fence();

        // issue NEXT chunk's nbmap loads (xvn arrived during gather);
        // their round-trip hides under the MLP below
        if (hn) {
#pragma unroll
            for (int p = 0; p < 4; ++p) {
                int i0 = (int)xvn[p].x, i1 = (int)xvn[p].y;
                nbn[p] = NBq[i0 * GRID_W + i1];
            }
        }

        // ---- MLP: 2 tiles of 16 points ----
#pragma unroll
        for (int t = 0; t < 2; ++t) {
            s16x8 ah = AH[t], al = AL[t];
            // L1: (ah+al) @ W1 -> 8 MFMA; W1 frags read from LDS per use
            f32x4 c1[4];
#pragma unroll
            for (int nt = 0; nt < 4; ++nt) {
                union { uint4 q; s16x8 v; } wc;
                wc.q = *(const uint4*)(w1b + (nt * 64 + lid) * 4);
                f32x4 cc = {0.f, 0.f, 0.f, 0.f};
                cc = __builtin_amdgcn_mfma_f32_16x16x32_bf16(al, wc.v, cc, 0, 0, 0);
                cc = __builtin_amdgcn_mfma_f32_16x16x32_bf16(ah, wc.v, cc, 0, 0, 0);
                c1[nt] = cc;
            }
            __builtin_amdgcn_wave_barrier();
#pragma unroll
            for (int nt = 0; nt < 4; ++nt)
#pragma unroll
                for (int r = 0; r < 4; r += 2) {
                    float v0 = fmaxf(c1[nt][r]     + b1v[nt], 0.f);
                    float v1 = fmaxf(c1[nt][r + 1] + b1v[nt], 0.f);
                    unsigned p0, p1; split2_packed(v0, v1, p0, p1);
                    hb[(quad * 4 + r)     * PSTR + nt * 16 + m16] = p0;
                    hb[(quad * 4 + r + 1) * PSTR + nt * 16 + m16] = p1;
                }
            lds_fence();

            // L2: (a2h+a2l) @ W2 -> 16 MFMA; W2 frags read from LDS per use
            f32x4 c2[4] = {{0.f,0.f,0.f,0.f},{0.f,0.f,0.f,0.f},{0.f,0.f,0.f,0.f},{0.f,0.f,0.f,0.f}};
#pragma unroll
            for (int s = 0; s < 2; ++s) {
                const unsigned* rp = hb + m16 * PSTR + s * 32 + quad * 8;
                uint4 h0 = *(const uint4*)rp;
                uint4 h1 = *(const uint4*)(rp + 4);
                s16x8 a2h = unpack8(h0, h1, SEL_HI);
                s16x8 a2l = unpack8(h0, h1, SEL_LO);
#pragma unroll
                for (int nt = 0; nt < 4; ++nt) {
                    union { uint4 q; s16x8 v; } wc;
                    wc.q = *(const uint4*)(w2b + ((s * 4 + nt) * 64 + lid) * 4);
                    c2[nt] = __builtin_amdgcn_mfma_f32_16x16x32_bf16(a2l, wc.v, c2[nt], 0, 0, 0);
                    c2[nt] = __builtin_amdgcn_mfma_f32_16x16x32_bf16(a2h, wc.v, c2[nt], 0, 0, 0);
                }
            }
            lds_fence();   // h1 reads drained before h2 overwrite
#pragma unroll
            for (int nt = 0; nt < 4; ++nt)
#pragma unroll
                for (int r = 0; r < 4; r += 2) {
                    float v0 = fmaxf(c2[nt][r]     + b2v[nt], 0.f);
                    float v1 = fmaxf(c2[nt][r + 1] + b2v[nt], 0.f);
                    unsigned p0, p1; split2_packed(v0, v1, p0, p1);
                    hb[(quad * 4 + r)     * PSTR + nt * 16 + m16] = p0;
                    hb[(quad * 4 + r + 1) * PSTR + nt * 16 + m16] = p1;
                }
            lds_fence();

            // L3: (a3h+a3l) @ W3p -> 4 MFMA (rows 0..2 valid)
            f32x4 c3 = {0.f, 0.f, 0.f, 0.f};
#pragma unroll
            for (int s = 0; s < 2; ++s) {
                const unsigned* rp = hb + m16 * PSTR + s * 32 + quad * 8;
                uint4 h0 = *(const uint4*)rp;
                uint4 h1 = *(const uint4*)(rp + 4);
                s16x8 a3h = unpack8(h0, h1, SEL_HI);
                s16x8 a3l = unpack8(h0, h1, SEL_LO);
                c3 = __builtin_amdgcn_mfma_f32_16x16x32_bf16(a3l, w3f[s], c3, 0, 0, 0);
                c3 = __builtin_amdgcn_mfma_f32_16x16x32_bf16(a3h, w3f[s], c3, 0, 0, 0);
            }
            lds_fence();   // h2 reads drained before next h-writes / next gather
#pragma unroll
            for (int r = 0; r < 4; ++r) {
                float v = (c3[r] + b3m) * sdm + mum;
                v = fminf(fmaxf(v, 0.f), 1.f);   // finite inputs: no NaN path
                int gpt = c * 32 + t * 16 + quad * 4 + r;
                if (m16 < 3 && gpt < npts) out[(size_t)gpt * 3 + m16] = v;
            }
        }

        // rotate pipeline registers
        if (hn) {
#pragma unroll
            for (int p = 0; p < 4; ++p) { xv[p] = xvn[p]; nb[p] = nbn[p]; }
        }
    }
}

extern "C" void kernel_launch(void* const* d_in, const int* in_sizes, int n_in,
                              void* d_out, int out_size, void* d_ws, size_t ws_size,
                              hipStream_t stream) {
    const float* x         = (const float*)d_in[0];
    const float* positions = (const float*)d_in[1];
    const int*   nbmap     = (const int*)d_in[2];
    const float* emb       = (const float*)d_in[3];
    const float* W1        = (const float*)d_in[4];
    const float* b1        = (const float*)d_in[5];
    const float* W2        = (const float*)d_in[6];
    const float* b2        = (const float*)d_in[7];
    const float* W3        = (const float*)d_in[8];
    const float* b3        = (const float*)d_in[9];
    const float* mu        = (const float*)d_in[10];
    const float* sd        = (const float*)d_in[11];
    float* out = (float*)d_out;

    int npts   = in_sizes[0] / 2;
    int n_embf = in_sizes[3];            // total floats in emb table
    size_t need = (size_t)n_embf * sizeof(_Float16);

    // persistent grid: 5 blocks/CU (LDS-limited: 30KB/block) = 20 waves/CU
    // target. 31250 chunks / 5120 waves ~= 6.1 per wave.
    int nch = (npts + 31) / 32;
    int blocks = 1280;
    int maxb = (nch + 3) / 4;
    if (blocks > maxb) blocks = maxb;

    if (d_ws != nullptr && ws_size >= need && (n_embf % 4) == 0) {
        _Float16* emb16 = (_Float16*)d_ws;
        int n4 = n_embf / 4;
        int cblocks = (n4 + 255) / 256;
        if (cblocks > 1024) cblocks = 1024;
        emb_cast_f16<<<cblocks, 256, 0, stream>>>(emb, emb16, n4);
        fused_persistent<true><<<blocks, 256, 0, stream>>>(x, positions, nbmap, emb16,
                                                           W1, b1, W2, b2, W3, b3, mu, sd,
                                                           out, npts);
    } else {
        fused_persistent<false><<<blocks, 256, 0, stream>>>(x, positions, nbmap, emb,
                                                            W1, b1, W2, b2, W3, b3, mu, sd,
                                                            out, npts);
    }
}

// Round 10
// 206.904 us; speedup vs baseline: 1.0465x; 1.0465x over previous
//
#include <hip/hip_runtime.h>
#include <hip/hip_bf16.h>

// CombinedModel R16: R15 retry — ds_swizzle offset must be a literal constant;
//   template-parameterize it. Theory unchanged (issue-pipe attack):
//   R14 post-mortem: FETCH -18% but time +7.5% == the +9.5% VALU added by cvts.
//   Across R6..R14: time tracks ISSUED WORK (vmem insts + VALU), not bytes, and
//   occupancy saturates ~36-42%. So: cut redundant issue at constant occupancy.
//   The gather's 8-lane c8-groups duplicate Pv loads + dist 8x (16 loads,
//   16 sqrt, ~128 VALU/lane/chunk for 128 unique dists). Dedup:
//     - each lane computes ONE dist for k = c8&3 (select id via cndmask chain;
//       one Pv load/p with 32 unique addrs instead of 4 loads x 8-dup)
//     - broadcast the 4 dists in each aligned 8-lane group via ds_swizzle
//       BitMode (and=0x18, or=k): offsets 0x18/0x38/0x58/0x78
//   Gather pos-path: 16->4 vmem insts, 16->4 sqrt, ~-60 VALU/lane/chunk.
//   Dist values BIT-IDENTICAL -> absmax must stay 0.015625 exactly.
//   All else = R13 (best, 113.4us): fp32 emb, hint 5 / 48-VGPR spill-free,
//   W1+W2 frags in block-shared LDS (30KB, 5 blocks/CU), grid 1280, LDS-staged
//   lat, split-bf16 MLP, cross-chunk x/nbmap pipeline, wave-private slabs,
//   single startup barrier.

typedef __attribute__((ext_vector_type(2))) float f32x2;
typedef __attribute__((ext_vector_type(4))) float f32x4;
typedef __attribute__((ext_vector_type(4))) int   i32x4;
typedef __attribute__((ext_vector_type(8))) short s16x8;

#define GRID_W  2048
#define LSTR    36   // lat row stride (dwords): 144 B rows, 16B-aligned
#define PSTR    68   // h row stride (dwords): 272 B rows, 16B-aligned
#define W2OFF   (4 * 32 * LSTR)     // dword offset of W2 frag table (2048 dw)
#define W1OFF   (W2OFF + 2048)      // dword offset of W1 frag table (1024 dw)
#define SEL_HI  0x05040100u
#define SEL_LO  0x07060302u
#define LGKM0   0xC07F   // s_waitcnt vmcnt(63) expcnt(7) lgkmcnt(0): DS-only drain

static __device__ __forceinline__ unsigned bits_bf2(__hip_bfloat162 h) {
    union { __hip_bfloat162 b; unsigned u; } cv; cv.b = h; return cv.u;
}
// split (v0,v1) into bf16 hi + bf16 lo residual; packed dword_i = hi_i | lo_i<<16
static __device__ __forceinline__ void split2_packed(float v0, float v1, unsigned &p0, unsigned &p1) {
    float2 f; f.x = v0; f.y = v1;
    unsigned hu = bits_bf2(__float22bfloat162_rn(f));
    float2 d;
    d.x = v0 - __uint_as_float(hu << 16);
    d.y = v1 - __uint_as_float(hu & 0xffff0000u);
    unsigned lu = bits_bf2(__float22bfloat162_rn(d));
    p0 = (hu & 0xffffu) | (lu << 16);
    p1 = (hu >> 16) | (lu & 0xffff0000u);
}
static __device__ __forceinline__ s16x8 unpack8(uint4 q0, uint4 q1, unsigned sel) {
    union { unsigned u[4]; s16x8 v; } r;
    r.u[0] = __builtin_amdgcn_perm(q0.y, q0.x, sel);
    r.u[1] = __builtin_amdgcn_perm(q0.w, q0.z, sel);
    r.u[2] = __builtin_amdgcn_perm(q1.y, q1.x, sel);
    r.u[3] = __builtin_amdgcn_perm(q1.w, q1.z, sel);
    return r.v;
}
// single-bf16 weight fragment: 8 consecutive fp32 -> 8 bf16 (rtn)
static __device__ __forceinline__ s16x8 load_wbf(const float* p) {
    f32x4 a = ((const f32x4*)p)[0];
    f32x4 b = ((const f32x4*)p)[1];
    union { unsigned u[4]; s16x8 v; } r;
    float2 f;
    f.x = a.x; f.y = a.y; r.u[0] = bits_bf2(__float22bfloat162_rn(f));
    f.x = a.z; f.y = a.w; r.u[1] = bits_bf2(__float22bfloat162_rn(f));
    f.x = b.x; f.y = b.y; r.u[2] = bits_bf2(__float22bfloat162_rn(f));
    f.x = b.z; f.y = b.w; r.u[3] = bits_bf2(__float22bfloat162_rn(f));
    return r.v;
}
static __device__ __forceinline__ void lds_fence() {
    __builtin_amdgcn_wave_barrier();
    __builtin_amdgcn_s_waitcnt(LGKM0);
    __builtin_amdgcn_wave_barrier();
}
// broadcast lane ((lane&0x18) | k) -> all 8 lanes of its group; OFFS is a
// compile-time literal (ds_swizzle requires a constant-integer offset).
// BitMode offset = (xor<<10)|(or<<5)|and: and=0x18 keeps group base, or=k.
template <int OFFS>
static __device__ __forceinline__ float swz_bcast(float v) {
    return __uint_as_float((unsigned)__builtin_amdgcn_ds_swizzle(
        (int)__float_as_uint(v), OFFS));
}

__global__ __launch_bounds__(256, 5) void fused_persistent(
    const float* __restrict__ x,          // [N,2]
    const float* __restrict__ positions,  // [N_POS,2]
    const int*   __restrict__ nbmap,      // [H,W,4]
    const float* __restrict__ emb,        // [N_POS,32]
    const float* __restrict__ W1,         // [64,32]
    const float* __restrict__ b1,         // [64]
    const float* __restrict__ W2,         // [64,64]
    const float* __restrict__ b2,         // [64]
    const float* __restrict__ W3,         // [3,64]
    const float* __restrict__ b3,         // [3]
    const float* __restrict__ mu,         // [3]
    const float* __restrict__ sd,         // [3]
    float* __restrict__ out,              // [N,3]
    int npts)
{
    const int tid  = threadIdx.x;
    const int w    = tid >> 6;
    const int lid  = tid & 63;
    const int quad = lid >> 4;
    const int m16  = lid & 15;
    const int c8   = lid & 7;    // gather: channel group (channels 4*c8 .. 4*c8+3)
    const int pr   = lid >> 3;   // gather: point row within pass (0..7)
    const int ksel = c8 & 3;     // gather: which neighbor this lane's dist covers

    const int nwav = gridDim.x * 4;
    const int wgid = blockIdx.x * 4 + w;
    const int NCH  = (npts + 31) >> 5;

    // LDS: [0,W2OFF) 4 wave-private lat/h slabs; [W2OFF,+2048) W2; [W1OFF,+1024) W1
    __shared__ __align__(16) unsigned lat_lds[W1OFF + 1024];   // 30 KB total
    unsigned* latw = lat_lds + w * 32 * LSTR;   // wave-private 32-row slab
    unsigned* hb   = latw;                      // h-buffer overlays dead lat slab
    unsigned* w2b  = lat_lds + W2OFF;           // block-shared W2 frags
    unsigned* w1b  = lat_lds + W1OFF;           // block-shared W1 frags

    // ---- stage W2 + W1 frags into LDS (wave 0 only; frags depend only on lid) ----
    if (w == 0) {
#pragma unroll
        for (int s = 0; s < 2; ++s)
#pragma unroll
            for (int nt = 0; nt < 4; ++nt) {
                union { s16x8 v; uint4 q; } cv;
                cv.v = load_wbf(W2 + (nt * 16 + m16) * 64 + s * 32 + quad * 8);
                *(uint4*)(w2b + ((s * 4 + nt) * 64 + lid) * 4) = cv.q;
            }
#pragma unroll
        for (int nt = 0; nt < 4; ++nt) {
            union { s16x8 v; uint4 q; } cv;
            cv.v = load_wbf(W1 + (nt * 16 + m16) * 32 + quad * 8);
            *(uint4*)(w1b + (nt * 64 + lid) * 4) = cv.q;
        }
    }
    __syncthreads();             // ONLY block barrier (startup); all waves reach it
    if (wgid >= NCH) return;     // after barrier: safe

    const f32x2* Xv  = (const f32x2*)x;
    const f32x2* Pv  = (const f32x2*)positions;
    const i32x4* NBq = (const i32x4*)nbmap;

    // ---- per-wave weights kept in VGPR: W3 only (8 regs) ----
    s16x8 w3f[2];
#pragma unroll
    for (int s = 0; s < 2; ++s) {
        if (m16 < 3) {
            w3f[s] = load_wbf(W3 + m16 * 64 + s * 32 + quad * 8);
        } else {
            s16x8 z = {0, 0, 0, 0, 0, 0, 0, 0};
            w3f[s] = z;
        }
    }
    float b1v[4], b2v[4];
#pragma unroll
    for (int nt = 0; nt < 4; ++nt) { b1v[nt] = b1[nt * 16 + m16]; b2v[nt] = b2[nt * 16 + m16]; }
    const int mm = (m16 < 3) ? m16 : 0;
    const float b3m = b3[mm], sdm = sd[mm], mum = mu[mm];

    // ---- pipeline prologue: x + nbmap for first chunk ----
    f32x2 xv[4], xvn[4];
    i32x4 nb[4], nbn[4];
#pragma unroll
    for (int p = 0; p < 4; ++p) {
        int g = wgid * 32 + p * 8 + pr;
        g = (g < npts) ? g : (npts - 1);
        xv[p] = Xv[g];
    }
#pragma unroll
    for (int p = 0; p < 4; ++p) {
        int i0 = (int)xv[p].x, i1 = (int)xv[p].y;   // x >= 0: trunc == floor
        nb[p] = NBq[i0 * GRID_W + i1];
    }

    for (int c = wgid; c < NCH; c += nwav) {
        const int cn = c + nwav;
        const bool hn = (cn < NCH);

        // issue NEXT chunk's x loads now: ~1500 cyc before they're consumed
        if (hn) {
#pragma unroll
            for (int p = 0; p < 4; ++p) {
                int g = cn * 32 + p * 8 + pr;
                g = (g < npts) ? g : (npts - 1);
                xvn[p] = Xv[g];
            }
        }

        // ---- gather chunk c: dist computed ONCE per (point,k) (lane k=c8&3),
        //      broadcast to the 8-lane channel group via ds_swizzle. Values
        //      bit-identical to the 8x-redundant version. ----
#pragma unroll
        for (int p = 0; p < 4; ++p) {
            f32x2 xvp = xv[p];
            float f0 = (float)(int)xvp.x, f1 = (float)(int)xvp.y;
            i32x4 n4 = nb[p];
            int ids[4] = {n4.x, n4.y, n4.z, n4.w};
            // this lane's dist: neighbor ksel
            int id_sel = ids[0];
            id_sel = (ksel == 1) ? ids[1] : id_sel;
            id_sel = (ksel == 2) ? ids[2] : id_sel;
            id_sel = (ksel == 3) ? ids[3] : id_sel;
            f32x2 pp = Pv[id_sel];                 // 1 load/p (32 unique addrs)
            float dx = pp.x - f0, dy = pp.y - f1;
            float dsel = sqrtf(dx * dx + dy * dy);
            // group-of-8 broadcasts: src lane = (lane & 0x18) | k
            float dd[4];
            dd[0] = swz_bcast<0x18>(dsel);
            dd[1] = swz_bcast<0x38>(dsel);
            dd[2] = swz_bcast<0x58>(dsel);
            dd[3] = swz_bcast<0x78>(dsel);
            float a0 = 0.f, a1 = 0.f, a2 = 0.f, a3 = 0.f;
#pragma unroll
            for (int k = 0; k < 4; ++k) {
                f32x4 e = *(const f32x4*)(emb + ids[k] * 32 + c8 * 4); // 8 lanes = full 128B row
                a0 = fmaf(dd[k], e.x, a0); a1 = fmaf(dd[k], e.y, a1);
                a2 = fmaf(dd[k], e.z, a2); a3 = fmaf(dd[k], e.w, a3);
            }
            unsigned p0, p1, p2, p3;
            split2_packed(a0, a1, p0, p1);
            split2_packed(a2, a3, p2, p3);
            uint4 pv; pv.x = p0; pv.y = p1; pv.z = p2; pv.w = p3;
            *(uint4*)(latw + (p * 8 + pr) * LSTR + c8 * 4) = pv;
        }
        lds_fence();

        // pre-read BOTH tiles' A-frags before hb overlay
        s16x8 AH[2], AL[2];
#pragma unroll
        for (int t = 0; t < 2; ++t) {
            const unsigned* ap = latw + (t * 16 + m16) * LSTR + quad * 8;
            uint4 q0 = *(const uint4*)ap;
            uint4 q1 = *(const uint4*)(ap + 4);
            AH[t] = unpack8(q0, q1, SEL_HI);
            AL[t] = unpack8(q0, q1, SEL_LO);
        }
        lds_fence();

        // issue NEXT chunk's nbmap loads (xvn arrived during gather);
        // their round-trip hides under the MLP below
        if (hn) {
#pragma unroll
            for (int p = 0; p < 4; ++p) {
                int i0 = (int)xvn[p].x, i1 = (int)xvn[p].y;
                nbn[p] = NBq[i0 * GRID_W + i1];
            }
        }

        // ---- MLP: 2 tiles of 16 points ----
#pragma unroll
        for (int t = 0; t < 2; ++t) {
            s16x8 ah = AH[t], al = AL[t];
            // L1: (ah+al) @ W1 -> 8 MFMA; W1 frags read from LDS per use
            f32x4 c1[4];
#pragma unroll
            for (int nt = 0; nt < 4; ++nt) {
                union { uint4 q; s16x8 v; } wc;
                wc.q = *(const uint4*)(w1b + (nt * 64 + lid) * 4);
                f32x4 cc = {0.f, 0.f, 0.f, 0.f};
                cc = __builtin_amdgcn_mfma_f32_16x16x32_bf16(al, wc.v, cc, 0, 0, 0);
                cc = __builtin_amdgcn_mfma_f32_16x16x32_bf16(ah, wc.v, cc, 0, 0, 0);
                c1[nt] = cc;
            }
            __builtin_amdgcn_wave_barrier();
#pragma unroll
            for (int nt = 0; nt < 4; ++nt)
#pragma unroll
                for (int r = 0; r < 4; r += 2) {
                    float v0 = fmaxf(c1[nt][r]     + b1v[nt], 0.f);
                    float v1 = fmaxf(c1[nt][r + 1] + b1v[nt], 0.f);
                    unsigned p0, p1; split2_packed(v0, v1, p0, p1);
                    hb[(quad * 4 + r)     * PSTR + nt * 16 + m16] = p0;
                    hb[(quad * 4 + r + 1) * PSTR + nt * 16 + m16] = p1;
                }
            lds_fence();

            // L2: (a2h+a2l) @ W2 -> 16 MFMA; W2 frags read from LDS per use
            f32x4 c2[4] = {{0.f,0.f,0.f,0.f},{0.f,0.f,0.f,0.f},{0.f,0.f,0.f,0.f},{0.f,0.f,0.f,0.f}};
#pragma unroll
            for (int s = 0; s < 2; ++s) {
                const unsigned* rp = hb + m16 * PSTR + s * 32 + quad * 8;
                uint4 h0 = *(const uint4*)rp;
                uint4 h1 = *(const uint4*)(rp + 4);
                s16x8 a2h = unpack8(h0, h1, SEL_HI);
                s16x8 a2l = unpack8(h0, h1, SEL_LO);
#pragma unroll
                for (int nt = 0; nt < 4; ++nt) {
                    union { uint4 q; s16x8 v; } wc;
                    wc.q = *(const uint4*)(w2b + ((s * 4 + nt) * 64 + lid) * 4);
                    c2[nt] = __builtin_amdgcn_mfma_f32_16x16x32_bf16(a2l, wc.v, c2[nt], 0, 0, 0);
                    c2[nt] = __builtin_amdgcn_mfma_f32_16x16x32_bf16(a2h, wc.v, c2[nt], 0, 0, 0);
                }
            }
            lds_fence();   // h1 reads drained before h2 overwrite
#pragma unroll
            for (int nt = 0; nt < 4; ++nt)
#pragma unroll
                for (int r = 0; r < 4; r += 2) {
                    float v0 = fmaxf(c2[nt][r]     + b2v[nt], 0.f);
                    float v1 = fmaxf(c2[nt][r + 1] + b2v[nt], 0.f);
                    unsigned p0, p1; split2_packed(v0, v1, p0, p1);
                    hb[(quad * 4 + r)     * PSTR + nt * 16 + m16] = p0;
                    hb[(quad * 4 + r + 1) * PSTR + nt * 16 + m16] = p1;
                }
            lds_fence();

            // L3: (a3h+a3l) @ W3p -> 4 MFMA (rows 0..2 valid)
            f32x4 c3 = {0.f, 0.f, 0.f, 0.f};
#pragma unroll
            for (int s = 0; s < 2; ++s) {
                const unsigned* rp = hb + m16 * PSTR + s * 32 + quad * 8;
                uint4 h0 = *(const uint4*)rp;
                uint4 h1 = *(const uint4*)(rp + 4);
                s16x8 a3h = unpack8(h0, h1, SEL_HI);
                s16x8 a3l = unpack8(h0, h1, SEL_LO);
                c3 = __builtin_amdgcn_mfma_f32_16x16x32_bf16(a3l, w3f[s], c3, 0, 0, 0);
                c3 = __builtin_amdgcn_mfma_f32_16x16x32_bf16(a3h, w3f[s], c3, 0, 0, 0);
            }
            lds_fence();   // h2 reads drained before next h-writes / next gather
#pragma unroll
            for (int r = 0; r < 4; ++r) {
                float v = (c3[r] + b3m) * sdm + mum;
                v = fminf(fmaxf(v, 0.f), 1.f);   // finite inputs: no NaN path
                int gpt = c * 32 + t * 16 + quad * 4 + r;
                if (m16 < 3 && gpt < npts) out[(size_t)gpt * 3 + m16] = v;
            }
        }

        // rotate pipeline registers
        if (hn) {
#pragma unroll
            for (int p = 0; p < 4; ++p) { xv[p] = xvn[p]; nb[p] = nbn[p]; }
        }
    }
}

extern "C" void kernel_launch(void* const* d_in, const int* in_sizes, int n_in,
                              void* d_out, int out_size, void* d_ws, size_t ws_size,
                              hipStream_t stream) {
    const float* x         = (const float*)d_in[0];
    const float* positions = (const float*)d_in[1];
    const int*   nbmap     = (const int*)d_in[2];
    const float* emb       = (const float*)d_in[3];
    const float* W1        = (const float*)d_in[4];
    const float* b1        = (const float*)d_in[5];
    const float* W2        = (const float*)d_in[6];
    const float* b2        = (const float*)d_in[7];
    const float* W3        = (const float*)d_in[8];
    const float* b3        = (const float*)d_in[9];
    const float* mu        = (const float*)d_in[10];
    const float* sd        = (const float*)d_in[11];
    float* out = (float*)d_out;

    int npts = in_sizes[0] / 2;
    // persistent grid: 5 blocks/CU (LDS-limited: 30KB/block) = 20 waves/CU
    // target. 31250 chunks / 5120 waves ~= 6.1 per wave.
    int nch = (npts + 31) / 32;
    int blocks = 1280;
    int maxb = (nch + 3) / 4;
    if (blocks > maxb) blocks = maxb;
    fused_persistent<<<blocks, 256, 0, stream>>>(x, positions, nbmap, emb,
                                                 W1, b1, W2, b2, W3, b3, mu, sd,
                                                 out, npts);
}